// Round 5
// baseline (379.234 us; speedup 1.0000x reference)
//
#include <hip/hip_runtime.h>
#include <cstdint>
#include <cstddef>

#define D_MODEL 1024
#define D_FF    2048
#define N_EXP   8
#define NTOK    4096          // B*S
#define NASSIGN (NTOK * 2)    // top-2
#define MAXTILE 72            // sum ceil(cnt_e/128) <= 64+7

typedef __bf16 bf16_t;
typedef bf16_t bf16x8 __attribute__((ext_vector_type(8)));
typedef float  f32x4  __attribute__((ext_vector_type(4)));

typedef __attribute__((address_space(3))) void       lds_void;
typedef const __attribute__((address_space(1))) void gl_void;

__device__ __forceinline__ unsigned short f2b(float f) {
  union { float f; unsigned u; } v; v.f = f;
  unsigned u = v.u;
  unsigned r = (u + 0x7FFFu + ((u >> 16) & 1u)) >> 16;  // RNE
  return (unsigned short)r;
}
__device__ __forceinline__ float b2f(unsigned short b) {
  union { unsigned u; float f; } v; v.u = ((unsigned)b) << 16; return v.f;
}

// ---------------- Prep: w1 transpose | w2 transpose | router, one launch ----------------
__device__ __forceinline__ void transpose_tile(
    const float* __restrict__ ein, unsigned short* __restrict__ eout,
    int R, int C, int bx, int by, float (*T)[65], int tid)
{
  const int c0 = bx * 64, r0 = by * 64;
  const int g = tid >> 4;        // 0..15
  const int m = tid & 15;        // 0..15
  #pragma unroll
  for (int i = 0; i < 4; ++i) {
    int r = i * 16 + g;
    float4 v = *(const float4*)(ein + (size_t)(r0 + r) * C + c0 + m * 4);
    T[r][m * 4 + 0] = v.x; T[r][m * 4 + 1] = v.y;
    T[r][m * 4 + 2] = v.z; T[r][m * 4 + 3] = v.w;
  }
  __syncthreads();
  #pragma unroll
  for (int i = 0; i < 4; ++i) {
    int c = i * 16 + g;
    ushort4 o;
    o.x = f2b(T[m * 4 + 0][c]); o.y = f2b(T[m * 4 + 1][c]);
    o.z = f2b(T[m * 4 + 2][c]); o.w = f2b(T[m * 4 + 3][c]);
    *(ushort4*)(eout + (size_t)(c0 + c) * R + r0 + m * 4) = o;
  }
}

__global__ __launch_bounds__(256) void prep_k(
    const float* __restrict__ x, const float* __restrict__ gw,
    const float* __restrict__ w1, const float* __restrict__ w2,
    unsigned short* __restrict__ w1t, unsigned short* __restrict__ w2t,
    int* __restrict__ eidx, float* __restrict__ ewt)
{
  __shared__ float T[64][65];
  const int bid = blockIdx.x;
  const int tid = threadIdx.x;

  if (bid < 4096) {
    // w1: [e][1024][2048] -> [e][2048][1024]   (C/64=32, R/64=16)
    int bx = bid & 31, by = (bid >> 5) & 15, e = bid >> 9;
    transpose_tile(w1 + (size_t)e * D_MODEL * D_FF,
                   w1t + (size_t)e * D_MODEL * D_FF,
                   D_MODEL, D_FF, bx, by, T, tid);
    return;
  }
  if (bid < 8192) {
    // w2: [e][2048][1024] -> [e][1024][2048]   (C/64=16, R/64=32)
    int b = bid - 4096;
    int bx = b & 15, by = (b >> 4) & 31, e = b >> 9;
    transpose_tile(w2 + (size_t)e * D_MODEL * D_FF,
                   w2t + (size_t)e * D_MODEL * D_FF,
                   D_FF, D_MODEL, bx, by, T, tid);
    return;
  }
  // router: fp32 logits, top-2, softmax
  const int rb = bid - 8192;
  const int wv = tid >> 6, lane = tid & 63;
  const int token = rb * 4 + wv;
  const float4* xr4 = (const float4*)(x + (size_t)token * D_MODEL);
  const float4* gw4 = (const float4*)gw;

  float acc[8] = {};
  #pragma unroll
  for (int it = 0; it < 4; ++it) {
    float4 xv = xr4[it * 64 + lane];
    int d0 = it * 256 + lane * 4;
    #pragma unroll
    for (int i = 0; i < 4; ++i) {
      int d = d0 + i;
      float4 g0 = gw4[d * 2];
      float4 g1 = gw4[d * 2 + 1];
      float xs = (i == 0) ? xv.x : (i == 1) ? xv.y : (i == 2) ? xv.z : xv.w;
      acc[0] += xs * g0.x; acc[1] += xs * g0.y;
      acc[2] += xs * g0.z; acc[3] += xs * g0.w;
      acc[4] += xs * g1.x; acc[5] += xs * g1.y;
      acc[6] += xs * g1.z; acc[7] += xs * g1.w;
    }
  }
  #pragma unroll
  for (int m = 1; m < 64; m <<= 1) {
    #pragma unroll
    for (int k = 0; k < 8; ++k) acc[k] += __shfl_xor(acc[k], m);
  }
  if (lane == 0) {
    int i1 = 0; float v1 = acc[0];
    #pragma unroll
    for (int k = 1; k < 8; ++k) if (acc[k] > v1) { v1 = acc[k]; i1 = k; }
    int i2 = -1; float v2 = -1e30f;
    #pragma unroll
    for (int k = 0; k < 8; ++k) if (k != i1 && acc[k] > v2) { v2 = acc[k]; i2 = k; }
    float t  = __expf(v2 - v1);
    float wa = 1.f / (1.f + t);
    float wb = t * wa;
    eidx[token * 2 + 0] = i1; eidx[token * 2 + 1] = i2;
    ewt [token * 2 + 0] = wa; ewt [token * 2 + 1] = wb;
  }
}

// ------- Scan: deterministic per-expert ranking + tile work-list. 1 block. -------
__global__ __launch_bounds__(256) void scan_k(
    const int* __restrict__ eidx, const float* __restrict__ ewt,
    int* __restrict__ counts, int* __restrict__ offsets,
    int* __restrict__ rowtok, float* __restrict__ rowwt, int* __restrict__ rowof,
    int* __restrict__ tile_e, int* __restrict__ tile_m0, int* __restrict__ tile_n)
{
  __shared__ int hist[256][9];   // stride 9: max 2-way (free)
  __shared__ int soff[8];
  const int t = threadIdx.x;

  int local[8] = {};
  #pragma unroll 4
  for (int i = 0; i < 32; ++i) local[eidx[t * 32 + i]]++;
  #pragma unroll
  for (int e = 0; e < 8; ++e) hist[t][e] = local[e];
  __syncthreads();

  for (int ofs = 1; ofs < 256; ofs <<= 1) {
    int v[8];
    if (t >= ofs) {
      #pragma unroll
      for (int e = 0; e < 8; ++e) v[e] = hist[t - ofs][e];
    }
    __syncthreads();
    if (t >= ofs) {
      #pragma unroll
      for (int e = 0; e < 8; ++e) hist[t][e] += v[e];
    }
    __syncthreads();
  }

  if (t == 0) {
    int o = 0, tt = 0;
    for (int e = 0; e < 8; ++e) {
      int c = hist[255][e];
      counts[e] = c;
      offsets[e] = o;
      soff[e] = o;
      int nt = (c + 127) >> 7;
      for (int i = 0; i < nt; ++i) { tile_e[tt] = e; tile_m0[tt] = i * 128; ++tt; }
      o += c;
    }
    tile_n[0] = tt;
  }
  __syncthreads();

  int run[8];
  #pragma unroll
  for (int e = 0; e < 8; ++e) run[e] = soff[e] + hist[t][e] - local[e];

  #pragma unroll 4
  for (int i = 0; i < 32; ++i) {
    int b = t * 32 + i;
    int e = eidx[b];
    int row = run[e]++;
    rowtok[row] = b >> 1;
    rowwt[row]  = ewt[b];
    rowof[b]    = row;
  }
}

// -------- Gather: block per row, x[token] -> bf16 Xe[row]. --------
__global__ __launch_bounds__(256) void gather_k(
    const float* __restrict__ x, const int* __restrict__ rowtok,
    unsigned short* __restrict__ Xe)
{
  const int row = blockIdx.x;
  const int token = rowtok[row];
  const float4* xr = (const float4*)(x + (size_t)token * D_MODEL);
  ushort4* dst = (ushort4*)(Xe + (size_t)row * D_MODEL);
  float4 v = xr[threadIdx.x];
  ushort4 o;
  o.x = f2b(v.x); o.y = f2b(v.y); o.z = f2b(v.z); o.w = f2b(v.w);
  dst[threadIdx.x] = o;
}

// ---------------- Segmented bf16 MFMA GEMM, 128x128 tile, BK=64 ----------------
// XOR-swizzled LDS: lane l stages global chunk (l&7)^(l>>3) so fragment
// ds_read_b128 at p=(kk*4+quad)^(col&7) is bank-conflict-free.
// MODE 1: Hout = bf16(silu(A.Bt^T))   MODE 2: Hout = bf16(rowwt * A.Bt^T)
template<int K, int N, int NT_LOG2, int MODE>
__global__ __launch_bounds__(256) void moe_gemm_k(
    const unsigned short* __restrict__ A,
    const unsigned short* __restrict__ Bt,
    unsigned short* __restrict__ Hout,
    const int* __restrict__ counts, const int* __restrict__ offsets,
    const float* __restrict__ rowwt,
    const int* __restrict__ tile_e, const int* __restrict__ tile_m0,
    const int* __restrict__ tile_n)
{
  const int t = blockIdx.x >> NT_LOG2;
  if (t >= tile_n[0]) return;
  const int e   = tile_e[t];
  const int m0  = tile_m0[t];
  const int n0  = (blockIdx.x & ((1 << NT_LOG2) - 1)) * 128;
  const int cnt = counts[e];
  const int base = offsets[e];

  __shared__ unsigned short lA[128 * 64];
  __shared__ unsigned short lB[128 * 64];

  const int tid = threadIdx.x;
  const int lane = tid & 63;
  const int wv = tid >> 6;
  const int wm = wv & 1, wn = wv >> 1;
  const int col = lane & 15, quad = lane >> 4;

  const unsigned short* Aseg = A + (size_t)base * K;
  const unsigned short* Bseg = Bt + (size_t)e * ((size_t)N * K);

  // staging geometry: segment s covers rows 8s..8s+7; lane l -> row s*8+(l>>3),
  // global chunk (l&7)^(l>>3), LDS dest = s*1024 + 16*l (hw-fixed)
  const int lrow = lane >> 3;
  const int gch  = (lane & 7) ^ lrow;

  f32x4 acc[4][4] = {};

  for (int k0 = 0; k0 < K; k0 += 64) {
    __syncthreads();
    #pragma unroll
    for (int r = 0; r < 4; ++r) {
      int s = r * 4 + wv;
      int row = s * 8 + lrow;
      const char* gA = (const char*)Aseg + ((size_t)(m0 + row) * K + k0) * 2 + gch * 16;
      const char* gB = (const char*)Bseg + ((size_t)(n0 + row) * K + k0) * 2 + gch * 16;
      __builtin_amdgcn_global_load_lds((gl_void*)gA, (lds_void*)((char*)lA + s * 1024), 16, 0, 0);
      __builtin_amdgcn_global_load_lds((gl_void*)gB, (lds_void*)((char*)lB + s * 1024), 16, 0, 0);
    }
    __syncthreads();

    #pragma unroll
    for (int kk = 0; kk < 2; ++kk) {
      bf16x8 af[4], bfr[4];
      #pragma unroll
      for (int i = 0; i < 4; ++i) {
        int r = wm * 64 + i * 16 + col;
        int p = ((kk << 2) | quad) ^ (col & 7);
        af[i] = *(const bf16x8*)(lA + r * 64 + p * 8);
      }
      #pragma unroll
      for (int j = 0; j < 4; ++j) {
        int r = wn * 64 + j * 16 + col;
        int p = ((kk << 2) | quad) ^ (col & 7);
        bfr[j] = *(const bf16x8*)(lB + r * 64 + p * 8);
      }
      #pragma unroll
      for (int i = 0; i < 4; ++i)
        #pragma unroll
        for (int j = 0; j < 4; ++j)
          acc[i][j] = __builtin_amdgcn_mfma_f32_16x16x32_bf16(af[i], bfr[j], acc[i][j], 0, 0, 0);
    }
  }

  // Epilogue. C/D layout: col = lane&15, row = quad*4 + reg  [m89/m91 verified]
  #pragma unroll
  for (int i = 0; i < 4; ++i) {
    #pragma unroll
    for (int reg = 0; reg < 4; ++reg) {
      int r = m0 + wm * 64 + i * 16 + quad * 4 + reg;
      if (r < cnt) {
        unsigned short* hrow = Hout + (size_t)(base + r) * N + (n0 + wn * 64 + col);
        if (MODE == 1) {
          #pragma unroll
          for (int j = 0; j < 4; ++j) {
            float v = acc[i][j][reg];
            float s = v / (1.f + __expf(-v));   // silu
            hrow[j * 16] = f2b(s);
          }
        } else {
          float wgt = rowwt[base + r];
          #pragma unroll
          for (int j = 0; j < 4; ++j)
            hrow[j * 16] = f2b(wgt * acc[i][j][reg]);
        }
      }
    }
  }
}

// ------- Combine: out[t] = Y[rowof[2t]] + Y[rowof[2t+1]] (weights pre-applied) -------
__global__ __launch_bounds__(256) void combine_k(
    const unsigned short* __restrict__ Y, const int* __restrict__ rowof,
    float* __restrict__ out)
{
  const int token = blockIdx.x;
  const int r1 = rowof[token * 2];
  const int r2 = rowof[token * 2 + 1];
  const int d4 = threadIdx.x;
  ushort4 a = *(const ushort4*)(Y + (size_t)r1 * D_MODEL + d4 * 4);
  ushort4 b = *(const ushort4*)(Y + (size_t)r2 * D_MODEL + d4 * 4);
  float4 o;
  o.x = b2f(a.x) + b2f(b.x);
  o.y = b2f(a.y) + b2f(b.y);
  o.z = b2f(a.z) + b2f(b.z);
  o.w = b2f(a.w) + b2f(b.w);
  *(float4*)(out + (size_t)token * D_MODEL + d4 * 4) = o;
}

extern "C" void kernel_launch(void* const* d_in, const int* in_sizes, int n_in,
                              void* d_out, int out_size, void* d_ws, size_t ws_size,
                              hipStream_t stream) {
  const float* x  = (const float*)d_in[0];
  const float* gw = (const float*)d_in[1];
  const float* w1 = (const float*)d_in[2];
  const float* w2 = (const float*)d_in[3];
  float* out = (float*)d_out;

  char* ws = (char*)d_ws;
  size_t off = 0;
  auto alloc = [&](size_t bytes) -> char* {
    char* p = ws + off; off += (bytes + 255) & ~(size_t)255; return p;
  };
  int*   ctrl    = (int*)alloc(1024);     // counts[8] | offsets[8] | tile_n | tiles
  int*   counts  = ctrl;
  int*   offsets = ctrl + 8;
  int*   tile_n  = ctrl + 16;
  int*   tile_e  = ctrl + 32;             // [MAXTILE]
  int*   tile_m0 = ctrl + 32 + MAXTILE;   // [MAXTILE]
  int*   eidx    = (int*)  alloc((size_t)NASSIGN * 4);
  float* ewt     = (float*)alloc((size_t)NASSIGN * 4);
  int*   rowtok  = (int*)  alloc((size_t)NASSIGN * 4);
  float* rowwt   = (float*)alloc((size_t)NASSIGN * 4);
  int*   rowof   = (int*)  alloc((size_t)NASSIGN * 4);
  unsigned short* Xe  = (unsigned short*)alloc((size_t)(NASSIGN + 128) * D_MODEL * 2);
  unsigned short* H   = (unsigned short*)alloc((size_t)(NASSIGN + 128) * D_FF * 2);
  unsigned short* Y   = (unsigned short*)alloc((size_t)(NASSIGN + 128) * D_MODEL * 2);
  unsigned short* w1t = (unsigned short*)alloc((size_t)N_EXP * D_MODEL * D_FF * 2);
  unsigned short* w2t = (unsigned short*)alloc((size_t)N_EXP * D_MODEL * D_FF * 2);

  prep_k<<<8192 + NTOK / 4, 256, 0, stream>>>(x, gw, w1, w2, w1t, w2t, eidx, ewt);
  scan_k<<<1, 256, 0, stream>>>(eidx, ewt, counts, offsets, rowtok, rowwt, rowof,
                                tile_e, tile_m0, tile_n);
  gather_k<<<NASSIGN, 256, 0, stream>>>(x, rowtok, Xe);

  moe_gemm_k<D_MODEL, D_FF, 4, 1><<<MAXTILE * 16, 256, 0, stream>>>(
      Xe, w1t, H, counts, offsets, rowwt, tile_e, tile_m0, tile_n);
  moe_gemm_k<D_FF, D_MODEL, 3, 2><<<MAXTILE * 8, 256, 0, stream>>>(
      H, w2t, Y, counts, offsets, rowwt, tile_e, tile_m0, tile_n);
  combine_k<<<NTOK, 256, 0, stream>>>(Y, rowof, out);
}

// Round 6
// 355.272 us; speedup vs baseline: 1.0674x; 1.0674x over previous
//
#include <hip/hip_runtime.h>
#include <cstdint>
#include <cstddef>

#define D_MODEL 1024
#define D_FF    2048
#define N_EXP   8
#define NTOK    4096          // B*S
#define NASSIGN (NTOK * 2)    // top-2
#define MAXTILE 72            // sum ceil(cnt_e/128) <= 64+7

typedef __bf16 bf16_t;
typedef bf16_t bf16x8 __attribute__((ext_vector_type(8)));
typedef float  f32x4  __attribute__((ext_vector_type(4)));

typedef __attribute__((address_space(3))) void       lds_void;
typedef const __attribute__((address_space(1))) void gl_void;

__device__ __forceinline__ unsigned short f2b(float f) {
  union { float f; unsigned u; } v; v.f = f;
  unsigned u = v.u;
  unsigned r = (u + 0x7FFFu + ((u >> 16) & 1u)) >> 16;  // RNE
  return (unsigned short)r;
}
__device__ __forceinline__ float b2f(unsigned short b) {
  union { unsigned u; float f; } v; v.u = ((unsigned)b) << 16; return v.f;
}

// ---------------- Prep: w1 transpose | w2 transpose | router, one launch ----------------
__device__ __forceinline__ void transpose_tile(
    const float* __restrict__ ein, unsigned short* __restrict__ eout,
    int R, int C, int bx, int by, float (*T)[65], int tid)
{
  const int c0 = bx * 64, r0 = by * 64;
  const int g = tid >> 4;        // 0..15
  const int m = tid & 15;        // 0..15
  #pragma unroll
  for (int i = 0; i < 4; ++i) {
    int r = i * 16 + g;
    float4 v = *(const float4*)(ein + (size_t)(r0 + r) * C + c0 + m * 4);
    T[r][m * 4 + 0] = v.x; T[r][m * 4 + 1] = v.y;
    T[r][m * 4 + 2] = v.z; T[r][m * 4 + 3] = v.w;
  }
  __syncthreads();
  #pragma unroll
  for (int i = 0; i < 4; ++i) {
    int c = i * 16 + g;
    ushort4 o;
    o.x = f2b(T[m * 4 + 0][c]); o.y = f2b(T[m * 4 + 1][c]);
    o.z = f2b(T[m * 4 + 2][c]); o.w = f2b(T[m * 4 + 3][c]);
    *(ushort4*)(eout + (size_t)(c0 + c) * R + r0 + m * 4) = o;
  }
}

__global__ __launch_bounds__(256) void prep_k(
    const float* __restrict__ x, const float* __restrict__ gw,
    const float* __restrict__ w1, const float* __restrict__ w2,
    unsigned short* __restrict__ w1t, unsigned short* __restrict__ w2t,
    int* __restrict__ eidx, float* __restrict__ ewt)
{
  __shared__ float T[64][65];
  const int bid = blockIdx.x;
  const int tid = threadIdx.x;

  if (bid < 4096) {
    // w1: [e][1024][2048] -> [e][2048][1024]
    int bx = bid & 31, by = (bid >> 5) & 15, e = bid >> 9;
    transpose_tile(w1 + (size_t)e * D_MODEL * D_FF,
                   w1t + (size_t)e * D_MODEL * D_FF,
                   D_MODEL, D_FF, bx, by, T, tid);
    return;
  }
  if (bid < 8192) {
    // w2: [e][2048][1024] -> [e][1024][2048]
    int b = bid - 4096;
    int bx = b & 15, by = (b >> 4) & 31, e = b >> 9;
    transpose_tile(w2 + (size_t)e * D_MODEL * D_FF,
                   w2t + (size_t)e * D_MODEL * D_FF,
                   D_FF, D_MODEL, bx, by, T, tid);
    return;
  }
  // router: fp32 logits, top-2, softmax
  const int rb = bid - 8192;
  const int wv = tid >> 6, lane = tid & 63;
  const int token = rb * 4 + wv;
  const float4* xr4 = (const float4*)(x + (size_t)token * D_MODEL);
  const float4* gw4 = (const float4*)gw;

  float acc[8] = {};
  #pragma unroll
  for (int it = 0; it < 4; ++it) {
    float4 xv = xr4[it * 64 + lane];
    int d0 = it * 256 + lane * 4;
    #pragma unroll
    for (int i = 0; i < 4; ++i) {
      int d = d0 + i;
      float4 g0 = gw4[d * 2];
      float4 g1 = gw4[d * 2 + 1];
      float xs = (i == 0) ? xv.x : (i == 1) ? xv.y : (i == 2) ? xv.z : xv.w;
      acc[0] += xs * g0.x; acc[1] += xs * g0.y;
      acc[2] += xs * g0.z; acc[3] += xs * g0.w;
      acc[4] += xs * g1.x; acc[5] += xs * g1.y;
      acc[6] += xs * g1.z; acc[7] += xs * g1.w;
    }
  }
  #pragma unroll
  for (int m = 1; m < 64; m <<= 1) {
    #pragma unroll
    for (int k = 0; k < 8; ++k) acc[k] += __shfl_xor(acc[k], m);
  }
  if (lane == 0) {
    int i1 = 0; float v1 = acc[0];
    #pragma unroll
    for (int k = 1; k < 8; ++k) if (acc[k] > v1) { v1 = acc[k]; i1 = k; }
    int i2 = -1; float v2 = -1e30f;
    #pragma unroll
    for (int k = 0; k < 8; ++k) if (k != i1 && acc[k] > v2) { v2 = acc[k]; i2 = k; }
    float t  = __expf(v2 - v1);
    float wa = 1.f / (1.f + t);
    float wb = t * wa;
    eidx[token * 2 + 0] = i1; eidx[token * 2 + 1] = i2;
    ewt [token * 2 + 0] = wa; ewt [token * 2 + 1] = wb;
  }
}

// ------- Scan: deterministic per-expert ranking + tile work-list. 1 block. -------
__global__ __launch_bounds__(256) void scan_k(
    const int* __restrict__ eidx, const float* __restrict__ ewt,
    int* __restrict__ counts, int* __restrict__ offsets,
    int* __restrict__ rowtok, float* __restrict__ rowwt, int* __restrict__ rowof,
    int* __restrict__ tile_e, int* __restrict__ tile_m0, int* __restrict__ tile_n)
{
  __shared__ int hist[256][9];   // stride 9: max 2-way (free)
  __shared__ int soff[8];
  const int t = threadIdx.x;

  int local[8] = {};
  #pragma unroll 4
  for (int i = 0; i < 32; ++i) local[eidx[t * 32 + i]]++;
  #pragma unroll
  for (int e = 0; e < 8; ++e) hist[t][e] = local[e];
  __syncthreads();

  for (int ofs = 1; ofs < 256; ofs <<= 1) {
    int v[8];
    if (t >= ofs) {
      #pragma unroll
      for (int e = 0; e < 8; ++e) v[e] = hist[t - ofs][e];
    }
    __syncthreads();
    if (t >= ofs) {
      #pragma unroll
      for (int e = 0; e < 8; ++e) hist[t][e] += v[e];
    }
    __syncthreads();
  }

  if (t == 0) {
    int o = 0, tt = 0;
    for (int e = 0; e < 8; ++e) {
      int c = hist[255][e];
      counts[e] = c;
      offsets[e] = o;
      soff[e] = o;
      int nt = (c + 127) >> 7;
      for (int i = 0; i < nt; ++i) { tile_e[tt] = e; tile_m0[tt] = i * 128; ++tt; }
      o += c;
    }
    tile_n[0] = tt;
  }
  __syncthreads();

  int run[8];
  #pragma unroll
  for (int e = 0; e < 8; ++e) run[e] = soff[e] + hist[t][e] - local[e];

  #pragma unroll 4
  for (int i = 0; i < 32; ++i) {
    int b = t * 32 + i;
    int e = eidx[b];
    int row = run[e]++;
    rowtok[row] = b >> 1;
    rowwt[row]  = ewt[b];
    rowof[b]    = row;
  }
}

// -------- Gather: block per row, x[token] -> bf16 Xe[row]. --------
__global__ __launch_bounds__(256) void gather_k(
    const float* __restrict__ x, const int* __restrict__ rowtok,
    unsigned short* __restrict__ Xe)
{
  const int row = blockIdx.x;
  const int token = rowtok[row];
  const float4* xr = (const float4*)(x + (size_t)token * D_MODEL);
  ushort4* dst = (ushort4*)(Xe + (size_t)row * D_MODEL);
  float4 v = xr[threadIdx.x];
  ushort4 o;
  o.x = f2b(v.x); o.y = f2b(v.y); o.z = f2b(v.z); o.w = f2b(v.w);
  dst[threadIdx.x] = o;
}

// ---------------- Segmented bf16 MFMA GEMM, 128x128 tile, BK=32 ----------------
// 16 KB LDS (R4 occupancy) + XOR swizzle (R5's zero bank conflicts):
//   64-B rows, 4 chunks; LDS slot (row, c) holds global chunk c ^ f(row),
//   f(row) = (row&3) ^ ((row>>2)&3). Fragment read: p = quad ^ f(col-derived).
//   Bank-set (row-parity, p): 8 sets x 8 lanes = uniform, conflict-free.
// MODE 1: Hout = bf16(silu(A.Bt^T))   MODE 2: Hout = bf16(rowwt * A.Bt^T)
template<int K, int N, int NT_LOG2, int MODE>
__global__ __launch_bounds__(256) void moe_gemm_k(
    const unsigned short* __restrict__ A,
    const unsigned short* __restrict__ Bt,
    unsigned short* __restrict__ Hout,
    const int* __restrict__ counts, const int* __restrict__ offsets,
    const float* __restrict__ rowwt,
    const int* __restrict__ tile_e, const int* __restrict__ tile_m0,
    const int* __restrict__ tile_n)
{
  const int t = blockIdx.x >> NT_LOG2;
  if (t >= tile_n[0]) return;
  const int e   = tile_e[t];
  const int m0  = tile_m0[t];
  const int n0  = (blockIdx.x & ((1 << NT_LOG2) - 1)) * 128;
  const int cnt = counts[e];
  const int base = offsets[e];

  __shared__ unsigned short lA[128 * 32];
  __shared__ unsigned short lB[128 * 32];

  const int tid = threadIdx.x;
  const int lane = tid & 63;
  const int wv = tid >> 6;
  const int wm = wv & 1, wn = wv >> 1;
  const int col = lane & 15, quad = lane >> 4;

  const unsigned short* Aseg = A + (size_t)base * K;
  const unsigned short* Bseg = Bt + (size_t)e * ((size_t)N * K);

  // staging: segment s (0..7) = 16 rows; lane l -> row s*16+(l>>2),
  // global chunk (l&3)^((l>>2)&3)^((l>>4)&3), LDS dest s*1024 + l*16 (hw-fixed)
  const int lrow = lane >> 2;
  const int gch  = (lane & 3) ^ ((lane >> 2) & 3) ^ ((lane >> 4) & 3);

  // fragment-read chunk (depends only on col)
  const int fsw = (col & 3) ^ ((col >> 2) & 3);

  f32x4 acc[4][4] = {};

  for (int k0 = 0; k0 < K; k0 += 32) {
    __syncthreads();
    #pragma unroll
    for (int r = 0; r < 2; ++r) {
      int s = r * 4 + wv;
      int row = s * 16 + lrow;
      const char* gA = (const char*)Aseg + ((size_t)(m0 + row) * K + k0) * 2 + gch * 16;
      const char* gB = (const char*)Bseg + ((size_t)(n0 + row) * K + k0) * 2 + gch * 16;
      __builtin_amdgcn_global_load_lds((gl_void*)gA, (lds_void*)((char*)lA + s * 1024), 16, 0, 0);
      __builtin_amdgcn_global_load_lds((gl_void*)gB, (lds_void*)((char*)lB + s * 1024), 16, 0, 0);
    }
    __syncthreads();

    bf16x8 af[4], bfr[4];
    #pragma unroll
    for (int i = 0; i < 4; ++i) {
      int r = wm * 64 + i * 16 + col;
      int p = quad ^ fsw;
      af[i] = *(const bf16x8*)(lA + r * 32 + p * 8);
    }
    #pragma unroll
    for (int j = 0; j < 4; ++j) {
      int r = wn * 64 + j * 16 + col;
      int p = quad ^ fsw;
      bfr[j] = *(const bf16x8*)(lB + r * 32 + p * 8);
    }
    #pragma unroll
    for (int i = 0; i < 4; ++i)
      #pragma unroll
      for (int j = 0; j < 4; ++j)
        acc[i][j] = __builtin_amdgcn_mfma_f32_16x16x32_bf16(af[i], bfr[j], acc[i][j], 0, 0, 0);
  }

  // Epilogue. C/D layout: col = lane&15, row = quad*4 + reg  [m89/m91 verified]
  #pragma unroll
  for (int i = 0; i < 4; ++i) {
    #pragma unroll
    for (int reg = 0; reg < 4; ++reg) {
      int r = m0 + wm * 64 + i * 16 + quad * 4 + reg;
      if (r < cnt) {
        unsigned short* hrow = Hout + (size_t)(base + r) * N + (n0 + wn * 64 + col);
        if (MODE == 1) {
          #pragma unroll
          for (int j = 0; j < 4; ++j) {
            float v = acc[i][j][reg];
            float s = v / (1.f + __expf(-v));   // silu
            hrow[j * 16] = f2b(s);
          }
        } else {
          float wgt = rowwt[base + r];
          #pragma unroll
          for (int j = 0; j < 4; ++j)
            hrow[j * 16] = f2b(wgt * acc[i][j][reg]);
        }
      }
    }
  }
}

// ------- Combine: out[t] = Y[rowof[2t]] + Y[rowof[2t+1]] (weights pre-applied) -------
__global__ __launch_bounds__(256) void combine_k(
    const unsigned short* __restrict__ Y, const int* __restrict__ rowof,
    float* __restrict__ out)
{
  const int token = blockIdx.x;
  const int r1 = rowof[token * 2];
  const int r2 = rowof[token * 2 + 1];
  const int d4 = threadIdx.x;
  ushort4 a = *(const ushort4*)(Y + (size_t)r1 * D_MODEL + d4 * 4);
  ushort4 b = *(const ushort4*)(Y + (size_t)r2 * D_MODEL + d4 * 4);
  float4 o;
  o.x = b2f(a.x) + b2f(b.x);
  o.y = b2f(a.y) + b2f(b.y);
  o.z = b2f(a.z) + b2f(b.z);
  o.w = b2f(a.w) + b2f(b.w);
  *(float4*)(out + (size_t)token * D_MODEL + d4 * 4) = o;
}

extern "C" void kernel_launch(void* const* d_in, const int* in_sizes, int n_in,
                              void* d_out, int out_size, void* d_ws, size_t ws_size,
                              hipStream_t stream) {
  const float* x  = (const float*)d_in[0];
  const float* gw = (const float*)d_in[1];
  const float* w1 = (const float*)d_in[2];
  const float* w2 = (const float*)d_in[3];
  float* out = (float*)d_out;

  char* ws = (char*)d_ws;
  size_t off = 0;
  auto alloc = [&](size_t bytes) -> char* {
    char* p = ws + off; off += (bytes + 255) & ~(size_t)255; return p;
  };
  int*   ctrl    = (int*)alloc(1024);     // counts[8] | offsets[8] | tile_n | tiles
  int*   counts  = ctrl;
  int*   offsets = ctrl + 8;
  int*   tile_n  = ctrl + 16;
  int*   tile_e  = ctrl + 32;             // [MAXTILE]
  int*   tile_m0 = ctrl + 32 + MAXTILE;   // [MAXTILE]
  int*   eidx    = (int*)  alloc((size_t)NASSIGN * 4);
  float* ewt     = (float*)alloc((size_t)NASSIGN * 4);
  int*   rowtok  = (int*)  alloc((size_t)NASSIGN * 4);
  float* rowwt   = (float*)alloc((size_t)NASSIGN * 4);
  int*   rowof   = (int*)  alloc((size_t)NASSIGN * 4);
  unsigned short* Xe  = (unsigned short*)alloc((size_t)(NASSIGN + 128) * D_MODEL * 2);
  unsigned short* H   = (unsigned short*)alloc((size_t)(NASSIGN + 128) * D_FF * 2);
  unsigned short* Y   = (unsigned short*)alloc((size_t)(NASSIGN + 128) * D_MODEL * 2);
  unsigned short* w1t = (unsigned short*)alloc((size_t)N_EXP * D_MODEL * D_FF * 2);
  unsigned short* w2t = (unsigned short*)alloc((size_t)N_EXP * D_MODEL * D_FF * 2);

  prep_k<<<8192 + NTOK / 4, 256, 0, stream>>>(x, gw, w1, w2, w1t, w2t, eidx, ewt);
  scan_k<<<1, 256, 0, stream>>>(eidx, ewt, counts, offsets, rowtok, rowwt, rowof,
                                tile_e, tile_m0, tile_n);
  gather_k<<<NASSIGN, 256, 0, stream>>>(x, rowtok, Xe);

  moe_gemm_k<D_MODEL, D_FF, 4, 1><<<MAXTILE * 16, 256, 0, stream>>>(
      Xe, w1t, H, counts, offsets, rowwt, tile_e, tile_m0, tile_n);
  moe_gemm_k<D_FF, D_MODEL, 3, 2><<<MAXTILE * 8, 256, 0, stream>>>(
      H, w2t, Y, counts, offsets, rowwt, tile_e, tile_m0, tile_n);
  combine_k<<<NTOK, 256, 0, stream>>>(Y, rowof, out);
}